// Round 1
// baseline (922.514 us; speedup 1.0000x reference)
//
#include <hip/hip_runtime.h>

// Problem: B=8, L=1024, H=1024, M=128, V=32 (V^2=1024). All fp32 in/out.
// Strategy: everything cast to fp16 for MFMA; big GEMM fuses pairs-construction
// into the A-fragment via per-K q-row scaling (A = k_frag * q_scale).
//
// WS layout (MiB offsets): x_h@0(16) q_h@16(2) k_h@18(2) wq_h@20(2) wk_h@22(2)
//                          we_h@24(2) wm_h@26(64KB) span@27(32KB)  => ~27.1 MB

typedef float   f32x4 __attribute__((ext_vector_type(4)));
typedef _Float16 f16x8 __attribute__((ext_vector_type(8)));

__device__ __forceinline__ void gld16(const void* g, void* l) {
  __builtin_amdgcn_global_load_lds(
      (const __attribute__((address_space(1))) void*)g,
      (__attribute__((address_space(3))) void*)l, 16, 0, 0);
}

// ---------------- weight fp32 -> fp16 convert (4 segments) ----------------
__global__ __launch_bounds__(256) void cvt_kernel(
    const float* __restrict__ wq, const float* __restrict__ wk,
    const float* __restrict__ we, const float* __restrict__ wm,
    _Float16* __restrict__ oq, _Float16* __restrict__ ok,
    _Float16* __restrict__ oe, _Float16* __restrict__ om) {
  int id = blockIdx.x * 256 + threadIdx.x;  // float4 units, total 794624
  const float* src; _Float16* dst; int off;
  if (id < 262144)      { src = wq; dst = oq; off = id; }
  else if (id < 524288) { src = wk; dst = ok; off = id - 262144; }
  else if (id < 786432) { src = we; dst = oe; off = id - 524288; }
  else                  { src = wm; dst = om; off = id - 786432; }
  float4 v = ((const float4*)src)[off];
  union { _Float16 h[4]; uint2 u; } o;
  o.h[0] = (_Float16)v.x; o.h[1] = (_Float16)v.y;
  o.h[2] = (_Float16)v.z; o.h[3] = (_Float16)v.w;
  ((uint2*)dst)[off] = o.u;
}

// ---------------- LayerNorm: x_enc (8192 x 1024) -> x_h fp16 ----------------
__global__ __launch_bounds__(256) void ln_kernel(
    const float* __restrict__ x, const float* __restrict__ g,
    const float* __restrict__ be, _Float16* __restrict__ xo) {
  const int row = blockIdx.x, t = threadIdx.x;
  const float4 v = ((const float4*)(x + (size_t)row * 1024))[t];
  float s1 = v.x + v.y + v.z + v.w;
  float s2 = v.x * v.x + v.y * v.y + v.z * v.z + v.w * v.w;
  #pragma unroll
  for (int m = 1; m < 64; m <<= 1) {
    s1 += __shfl_xor(s1, m, 64);
    s2 += __shfl_xor(s2, m, 64);
  }
  __shared__ float red[8];
  const int w = t >> 6, lane = t & 63;
  if (lane == 0) { red[w * 2] = s1; red[w * 2 + 1] = s2; }
  __syncthreads();
  s1 = red[0] + red[2] + red[4] + red[6];
  s2 = red[1] + red[3] + red[5] + red[7];
  const float mu = s1 * (1.f / 1024.f);
  const float var = s2 * (1.f / 1024.f) - mu * mu;
  const float rs = rsqrtf(var + 1e-5f);
  const float4 gv = ((const float4*)g)[t];
  const float4 bv = ((const float4*)be)[t];
  union { _Float16 h[4]; uint2 u; } o;
  o.h[0] = (_Float16)((v.x - mu) * rs * gv.x + bv.x);
  o.h[1] = (_Float16)((v.y - mu) * rs * gv.y + bv.y);
  o.h[2] = (_Float16)((v.z - mu) * rs * gv.z + bv.z);
  o.h[3] = (_Float16)((v.w - mu) * rs * gv.w + bv.w);
  ((uint2*)(xo + (size_t)row * 1024))[t] = o.u;
}

// ------------- q/k GEMM: gathered masked_x (1024x1024) @ W^T, NT -------------
// 64x64 tile, BK=32, 4 waves: wave w owns m-subtile w x 4 n-subtiles.
__global__ __launch_bounds__(256, 4) void qk_gemm(
    const _Float16* __restrict__ xh, const _Float16* __restrict__ wq,
    const _Float16* __restrict__ wk, const int* __restrict__ midx,
    _Float16* __restrict__ qout, _Float16* __restrict__ kout) {
  __shared__ _Float16 at[64 * 32];
  __shared__ _Float16 bt[64 * 32];
  const int tid = threadIdx.x, w = tid >> 6, lane = tid & 63;
  const int l15 = lane & 15, quad = lane >> 4;
  const int ntile = blockIdx.x, rtile = blockIdx.y, mat = blockIdx.z;
  const _Float16* wmat = mat ? wk : wq;
  _Float16* outp = mat ? kout : qout;

  // staging: thread tid stages 16B chunk tid; row=tid/4, col8=(tid%4)*8
  const int arow = tid >> 2;           // 0..63
  const int acol = (tid & 3) * 8;      // fp16 elems
  const int grow = rtile * 64 + arow;  // 0..1023 => (b,m)
  const int b = grow >> 7, m = grow & 127;
  const int src = midx[b * 128 + m];   // gather row in L
  const _Float16* agp = xh + ((size_t)(b * 1024 + src)) * 1024 + acol;
  const _Float16* bgp = wmat + (size_t)(ntile * 64 + arow) * 1024 + acol;
  char* aldst = (char*)at + w * 1024;  // wave-uniform base; HW adds lane*16
  char* bldst = (char*)bt + w * 1024;

  f32x4 acc[4];
  const f32x4 zero = {0.f, 0.f, 0.f, 0.f};
  #pragma unroll
  for (int ns = 0; ns < 4; ++ns) acc[ns] = zero;

  for (int s = 0; s < 32; ++s) {
    const int kk = s * 32;
    gld16(agp + kk, aldst);
    gld16(bgp + kk, bldst);
    __syncthreads();
    const f16x8 af = *(const f16x8*)&at[(w * 16 + l15) * 32 + quad * 8];
    #pragma unroll
    for (int ns = 0; ns < 4; ++ns) {
      const f16x8 bf = *(const f16x8*)&bt[(ns * 16 + l15) * 32 + quad * 8];
      acc[ns] = __builtin_amdgcn_mfma_f32_16x16x32_f16(af, bf, acc[ns], 0, 0, 0);
    }
    __syncthreads();
  }
  #pragma unroll
  for (int ns = 0; ns < 4; ++ns) {
    const int col = ntile * 64 + ns * 16 + l15;
    #pragma unroll
    for (int r = 0; r < 4; ++r) {
      const int row = rtile * 64 + w * 16 + quad * 4 + r;
      outp[(size_t)row * 1024 + col] = (_Float16)acc[ns][r];
    }
  }
}

// ---- big GEMM: logits[(b,i,j), v] = sum_h q[b,i,h]*k[b,j,h]*We[v,h] ----
// Block = fixed (b,i) x v-tile(128). Rows = all j (0..127). BK=32, K=1024.
// A-frag = k-frag (from LDS) * q-scale (wave-uniform per-K row, broadcast read).
__global__ __launch_bounds__(256, 3) void big_gemm(
    const _Float16* __restrict__ qf, const _Float16* __restrict__ kf,
    const _Float16* __restrict__ wemb, float* __restrict__ out) {
  __shared__ _Float16 kt[128 * 32];    // k[b, 0:128, kk:kk+32]
  __shared__ _Float16 btile[128 * 32]; // We[v0:v0+128, kk:kk+32]
  __shared__ _Float16 qrow[1024];      // q[b, i, :]

  const int tid = threadIdx.x, w = tid >> 6, lane = tid & 63;
  const int l15 = lane & 15, quad = lane >> 4;
  const int vtile = blockIdx.x;        // 0..7
  const int rt = blockIdx.y;           // 0..1023
  const int b = rt >> 7, i = rt & 127;
  const int wm = w >> 1, wn = w & 1;   // 2x2 wave grid over 128x128

  const _Float16* kbase = kf + (size_t)b * 128 * 1024;
  const _Float16* qbase = qf + (size_t)(b * 128 + i) * 1024;
  const _Float16* wbase = wemb + (size_t)vtile * 128 * 1024;

  // stage q row (2 KB) once via waves 0,1
  if (w < 2) gld16(qbase + w * 512 + lane * 8, (char*)qrow + w * 1024);

  f32x4 acc[4][4];
  const f32x4 zero = {0.f, 0.f, 0.f, 0.f};
  #pragma unroll
  for (int a = 0; a < 4; ++a)
    #pragma unroll
    for (int c = 0; c < 4; ++c) acc[a][c] = zero;

  const int srow0 = w * 32 + (lane >> 2);  // staging row (p adds 16)
  const int scol = (lane & 3) * 8;         // fp16 elems

  for (int s = 0; s < 32; ++s) {
    const int kk = s * 32;
    #pragma unroll
    for (int p = 0; p < 2; ++p) {
      const int r = srow0 + p * 16;
      gld16(kbase + (size_t)r * 1024 + kk + scol,
            (char*)kt + w * 2048 + p * 1024);
      gld16(wbase + (size_t)r * 1024 + kk + scol,
            (char*)btile + w * 2048 + p * 1024);
    }
    __syncthreads();

    const f16x8 qs = *(const f16x8*)&qrow[kk + quad * 8];  // broadcast read
    f16x8 af[4], bf[4];
    #pragma unroll
    for (int ms = 0; ms < 4; ++ms) {
      const f16x8 kfr = *(const f16x8*)&kt[(wm * 64 + ms * 16 + l15) * 32 + quad * 8];
      af[ms] = kfr * qs;  // 4x v_pk_mul_f16: pairs built in-register
    }
    #pragma unroll
    for (int ns = 0; ns < 4; ++ns)
      bf[ns] = *(const f16x8*)&btile[(wn * 64 + ns * 16 + l15) * 32 + quad * 8];
    #pragma unroll
    for (int ms = 0; ms < 4; ++ms)
      #pragma unroll
      for (int ns = 0; ns < 4; ++ns)
        acc[ms][ns] = __builtin_amdgcn_mfma_f32_16x16x32_f16(af[ms], bf[ns],
                                                             acc[ms][ns], 0, 0, 0);
    __syncthreads();
  }

  const size_t nbase = (size_t)rt * 128;  // logits row base
  #pragma unroll
  for (int ms = 0; ms < 4; ++ms) {
    const int j0 = wm * 64 + ms * 16 + quad * 4;
    #pragma unroll
    for (int ns = 0; ns < 4; ++ns) {
      const int col = vtile * 128 + wn * 64 + ns * 16 + l15;
      #pragma unroll
      for (int r = 0; r < 4; ++r)
        out[(nbase + j0 + r) * 1024 + col] = acc[ms][ns][r];
    }
  }
}

// ------------- mlm_logits: x_h (8192x1024) @ W_mlm^T (32x1024) -------------
// one wave per row; lane: v = lane&31, half-row part = lane>>5.
__global__ __launch_bounds__(256) void mlm_kernel(
    const _Float16* __restrict__ xh, const _Float16* __restrict__ wm,
    float* __restrict__ out) {
  const int w = threadIdx.x >> 6, lane = threadIdx.x & 63;
  const int row = blockIdx.x * 4 + w;
  const int v = lane & 31, part = lane >> 5;
  const f16x8* xr = (const f16x8*)(xh + (size_t)row * 1024 + part * 512);
  const f16x8* wr = (const f16x8*)(wm + (size_t)v * 1024 + part * 512);
  float acc = 0.f;
  #pragma unroll 8
  for (int it = 0; it < 64; ++it) {
    const f16x8 p = xr[it] * wr[it];
    #pragma unroll
    for (int e = 0; e < 8; ++e) acc += (float)p[e];
  }
  acc += __shfl_xor(acc, 32, 64);
  if (part == 0) out[(size_t)row * 32 + v] = acc;
}

// ------- span masks: in_span, mask_aa (out), diag_mask (out), ws copy -------
__global__ __launch_bounds__(256) void span_kernel(
    const int* __restrict__ midx, float* __restrict__ mask_aa,
    float* __restrict__ diag, float* __restrict__ span_ws) {
  __shared__ float flag[1024];
  const int b = blockIdx.x, t = threadIdx.x;
  for (int p = t; p < 1024; p += 256) flag[p] = 0.f;
  __syncthreads();
  if (t < 128) flag[midx[b * 128 + t]] = 1.f;
  __syncthreads();
  for (int p = t; p < 1024; p += 256) {
    const float f = flag[p];
    mask_aa[b * 1024 + p] = f;
    span_ws[b * 1024 + p] = f;
  }
  for (int p = t; p < 16384; p += 256)
    diag[b * 16384 + p] = ((p >> 7) == (p & 127)) ? 1.f : 0.f;
}

// ---------------- pair_mask_aa[b,i,j] = s[b,i]*s[b,j] (8.4M f32) ----------------
__global__ __launch_bounds__(256) void pairmask_kernel(
    const float* __restrict__ span_ws, float* __restrict__ out) {
  const int id = blockIdx.x * 256 + threadIdx.x;  // float4 units, 2M total
  const int b = id >> 18;
  const int rem = id & 262143;
  const int i = rem >> 8;
  const int j4 = rem & 255;
  const float si = span_ws[b * 1024 + i];
  const float4 sj = ((const float4*)(span_ws + b * 1024))[j4];
  float4 o;
  o.x = si * sj.x; o.y = si * sj.y; o.z = si * sj.z; o.w = si * sj.w;
  ((float4*)out)[id] = o;
}

extern "C" void kernel_launch(void* const* d_in, const int* in_sizes, int n_in,
                              void* d_out, int out_size, void* d_ws, size_t ws_size,
                              hipStream_t stream) {
  const float* x_enc = (const float*)d_in[0];
  const float* gam   = (const float*)d_in[1];
  const float* bet   = (const float*)d_in[2];
  const float* Wq    = (const float*)d_in[3];
  const float* Wk    = (const float*)d_in[4];
  const float* We    = (const float*)d_in[5];
  const float* Wm    = (const float*)d_in[6];
  const int*   midx  = (const int*)d_in[7];
  float* out = (float*)d_out;

  char* ws = (char*)d_ws;
  _Float16* x_h  = (_Float16*)(ws);
  _Float16* q_h  = (_Float16*)(ws + ((size_t)16 << 20));
  _Float16* k_h  = (_Float16*)(ws + ((size_t)18 << 20));
  _Float16* wq_h = (_Float16*)(ws + ((size_t)20 << 20));
  _Float16* wk_h = (_Float16*)(ws + ((size_t)22 << 20));
  _Float16* we_h = (_Float16*)(ws + ((size_t)24 << 20));
  _Float16* wm_h = (_Float16*)(ws + ((size_t)26 << 20));
  float* span_ws = (float*)(ws + ((size_t)27 << 20));

  float* o_logits = out;                        // 131072 x 1024
  float* o_mlm    = out + (size_t)134217728;    // 8192 x 32
  float* o_diag   = o_mlm + 262144;             // 131072
  float* o_maskaa = o_diag + 131072;            // 8192
  float* o_pair   = o_maskaa + 8192;            // 8388608

  cvt_kernel<<<3104, 256, 0, stream>>>(Wq, Wk, We, Wm, wq_h, wk_h, we_h, wm_h);
  ln_kernel<<<8192, 256, 0, stream>>>(x_enc, gam, bet, x_h);
  qk_gemm<<<dim3(16, 16, 2), 256, 0, stream>>>(x_h, wq_h, wk_h, midx, q_h, k_h);
  big_gemm<<<dim3(8, 1024), 256, 0, stream>>>(q_h, k_h, we_h, o_logits);
  mlm_kernel<<<2048, 256, 0, stream>>>(x_h, wm_h, o_mlm);
  span_kernel<<<8, 256, 0, stream>>>(midx, o_maskaa, o_diag, span_ws);
  pairmask_kernel<<<8192, 256, 0, stream>>>(span_ws, o_pair);
}